// Round 1
// 119.885 us; speedup vs baseline: 1.0295x; 1.0295x over previous
//
#include <hip/hip_runtime.h>
#include <math.h>

#define EPS  1e-6f
#define DD   256
#define NSUP 5
#define NQ   8
#define SEQ  13
#define L2E  1.44269504088896f
#define LN2  0.693147180559945f
#define NEP  2048            // episodes
#define NROW 16384           // NEP*NQ query rows
#define NCOL 2048            // anchor columns

typedef short bf16x8 __attribute__((ext_vector_type(8)));
typedef unsigned short u16x4 __attribute__((ext_vector_type(4)));
typedef float f32x4  __attribute__((ext_vector_type(4)));

__device__ __forceinline__ ushort f2bf(float f) {
  union { float f; unsigned u; } v; v.f = f;
  unsigned r = v.u + 0x7FFFu + ((v.u >> 16) & 1u);   // round-to-nearest-even
  return (ushort)(r >> 16);
}
__device__ __forceinline__ float bf2f(short u) {
  union { unsigned u; float f; } v; v.u = ((unsigned)(unsigned short)u) << 16;
  return v.f;
}

// ---------------------------------------------------------------------------
// prep (r8-proven): anchors/queries in MFMA-fragment-SWIZZLED order; element
// (c,d) -> ushort idx (((c>>4)*8+(d>>5))*64 + ((d>>3)&3)*16 + (c&15))*8+(d&7).
// cb[c] = -log2(e)*(sum(a^2) - 2*eps*sum(a)); row-constant cq cancels.
// Zeroes accum/fincount (ws is re-poisoned before every call).
// ---------------------------------------------------------------------------
__global__ __launch_bounds__(256) void proto_prep(
    const float* __restrict__ x, float* __restrict__ cb,
    ushort* __restrict__ Asw, ushort* __restrict__ Qsw,
    float* __restrict__ accum, int* __restrict__ fincount) {
  const int tid = threadIdx.x, g = tid >> 6, l = tid & 63;
  const int n = blockIdx.x * 4 + g;
  if (blockIdx.x == 0 && tid == 0) { accum[0] = 0.f; accum[1] = 0.f; fincount[0] = 0; }

  const float4* xr4 = (const float4*)(x + (size_t)n * SEQ * DD);

  const int d0   = l * 4;
  const int kk   = d0 >> 5, quad = (d0 >> 3) & 3, j = d0 & 7;   // j in {0,4}
  const size_t chunk_d = (size_t)kk * 64 + (size_t)quad * 16;

  float4 a = {0.f, 0.f, 0.f, 0.f};
  #pragma unroll
  for (int s = 0; s < NSUP; ++s) {
    float4 v = xr4[s * 64 + l];
    a.x += v.x; a.y += v.y; a.z += v.z; a.w += v.w;
  }
  a.x *= 0.2f; a.y *= 0.2f; a.z *= 0.2f; a.w *= 0.2f;
  {
    const size_t idx = (((size_t)(n >> 4) * 8) * 64 + chunk_d + (n & 15)) * 8 + j;
    u16x4 o = {f2bf(a.x), f2bf(a.y), f2bf(a.z), f2bf(a.w)};
    *(u16x4*)(Asw + idx) = o;
  }
  float s1 = a.x + a.y + a.z + a.w;
  float s2 = a.x * a.x + a.y * a.y + a.z * a.z + a.w * a.w;
  #pragma unroll
  for (int off = 32; off; off >>= 1) {
    s1 += __shfl_xor(s1, off);
    s2 += __shfl_xor(s2, off);
  }
  if (l == 0) cb[n] = -L2E * (s2 - 2.f * EPS * s1);

  #pragma unroll
  for (int s = 0; s < NQ; ++s) {
    float4 q = xr4[(NSUP + s) * 64 + l];
    const int row = n * NQ + s;
    const size_t idx = (((size_t)(row >> 4) * 8) * 64 + chunk_d + (row & 15)) * 8 + j;
    u16x4 o = {f2bf(q.x), f2bf(q.y), f2bf(q.z), f2bf(q.w)};
    *(u16x4*)(Qsw + idx) = o;
  }
}

// ---------------------------------------------------------------------------
// main: 256 blocks x 512 threads = 8 waves/block, 1 block/CU -> 2 waves/SIMD.
// r13 theory: at 1 wave/SIMD (previous (256,1) config) MfmaUtil+VALUBusy was
// only 42% -- pure latency exposure, no TLP. VGPR_Count=148 fits the 256-reg
// budget of 2 waves/SIMD with the ping-pong prefetch intact (the (256,1)
// grant was only needed for older 88-92-reg-budget structures). Wave w now
// owns a 256-col stripe (16 tiles); per-CU B traffic UNCHANGED (same block
// covers same 64 rows x 2048 cols). Per tile: 32 MFMA in 4 independent
// chains + 16 slot updates; two waves/SIMD overlap one wave's MFMA burst
// with the other's VALU softmax section.
// MFMA layouts (verified): A m=lane&15,k=quad*8+j ; B n=lane&15,k=quad*8+j ;
// C col=lane&15,row=quad*4+reg.
// ---------------------------------------------------------------------------
__global__ __launch_bounds__(512) void proto_main(
    const ushort* __restrict__ Qsw, const ushort* __restrict__ Asw,
    const float* __restrict__ cb, const int* __restrict__ label,
    float* __restrict__ accum, int* __restrict__ fincount,
    float* __restrict__ out) {
  const int tid  = threadIdx.x;
  const int wid  = tid >> 6, lane = tid & 63;
  const int quad = lane >> 4, lcol = lane & 15;
  const int r0   = blockIdx.x * 64;

  const bf16x8* qb = (const bf16x8*)Qsw;
  const bf16x8* bb = (const bf16x8*)Asw;

  // resident A fragments: 4 row-sets x 8 K-chunks (coalesced loads)
  bf16x8 af[4][8];
  #pragma unroll
  for (int set = 0; set < 4; ++set) {
    const size_t base = ((size_t)((r0 >> 4) + set) * 8) * 64 + lane;
    #pragma unroll
    for (int kk = 0; kk < 8; ++kk) af[set][kk] = qb[base + (size_t)kk * 64];
  }

  float m[4][4], s[4][4];
  int   bi[4][4];
  #pragma unroll
  for (int set = 0; set < 4; ++set)
    #pragma unroll
    for (int i = 0; i < 4; ++i) {
      m[set][i] = -1e30f; s[set][i] = 0.f; bi[set][i] = 0x7fffffff;
    }

  auto process = [&](int T, bf16x8* B) {
    f32x4 c0 = {0.f, 0.f, 0.f, 0.f}, c1 = {0.f, 0.f, 0.f, 0.f};
    f32x4 c2 = {0.f, 0.f, 0.f, 0.f}, c3 = {0.f, 0.f, 0.f, 0.f};
    #pragma unroll
    for (int kk = 0; kk < 8; ++kk) {
      c0 = __builtin_amdgcn_mfma_f32_16x16x32_bf16(af[0][kk], B[kk], c0, 0, 0, 0);
      c1 = __builtin_amdgcn_mfma_f32_16x16x32_bf16(af[1][kk], B[kk], c1, 0, 0, 0);
      c2 = __builtin_amdgcn_mfma_f32_16x16x32_bf16(af[2][kk], B[kk], c2, 0, 0, 0);
      c3 = __builtin_amdgcn_mfma_f32_16x16x32_bf16(af[3][kk], B[kk], c3, 0, 0, 0);
    }
    const int   colIdx = T * 16 + lcol;
    const float cbv    = cb[colIdx];       // 64-B broadcast segment
    #pragma unroll
    for (int set = 0; set < 4; ++set) {
      #pragma unroll
      for (int i = 0; i < 4; ++i) {
        float cv = (set == 0) ? c0[i] : (set == 1) ? c1[i]
                 : (set == 2) ? c2[i] : c3[i];
        float v2 = fmaf(cv, 2.f * L2E, cbv);     // log2-frame shifted logit
        float dv = v2 - m[set][i];
        bool  gt = dv > 0.f;
        float e  = exp2f(-fabsf(dv));            // single non-unit exp factor
        s[set][i]  = fmaf(s[set][i], gt ? e : 1.f, gt ? 1.f : e);
        m[set][i]  = fmaxf(m[set][i], v2);
        bi[set][i] = gt ? colIdx : bi[set][i];   // strict >: first max wins
      }
    }
  };

  const int T0 = wid * 16;                       // 8 waves x 16 tiles = 128
  bf16x8 buf0[8], buf1[8];
  #pragma unroll
  for (int kk = 0; kk < 8; ++kk)
    buf0[kk] = bb[((size_t)T0 * 8 + (size_t)kk) * 64 + lane];

  #pragma unroll 1
  for (int t = 0; t < 16; t += 2) {
    {
      const int Tn = T0 + t + 1;                             // always valid
      #pragma unroll
      for (int kk = 0; kk < 8; ++kk)
        buf1[kk] = bb[((size_t)Tn * 8 + (size_t)kk) * 64 + lane];
    }
    process(T0 + t, buf0);
    {
      const int Tm = (t + 2 < 16) ? T0 + t + 2 : T0 + t + 1; // clamp tail
      #pragma unroll
      for (int kk = 0; kk < 8; ++kk)
        buf0[kk] = bb[((size_t)Tm * 8 + (size_t)kk) * 64 + lane];
    }
    process(T0 + t + 1, buf1);
  }

  // merge across the 16 lanes sharing rows (cols differ)
  #pragma unroll
  for (int mask = 1; mask < 16; mask <<= 1) {
    #pragma unroll
    for (int set = 0; set < 4; ++set)
      #pragma unroll
      for (int i = 0; i < 4; ++i) {
        float om = __shfl_xor(m[set][i], mask);
        float os = __shfl_xor(s[set][i], mask);
        int   oi = __shfl_xor(bi[set][i], mask);
        float nm = fmaxf(m[set][i], om);
        s[set][i] = s[set][i] * exp2f(m[set][i] - nm) + os * exp2f(om - nm);
        bool better = (om > m[set][i]) || (om == m[set][i] && oi < bi[set][i]);
        bi[set][i] = better ? oi : bi[set][i];
        m[set][i]  = nm;
      }
  }

  __shared__ float sm[8][64], ssh[8][64], slab[64];
  __shared__ int   sbi[8][64];
  if (lcol == 0) {
    #pragma unroll
    for (int set = 0; set < 4; ++set)
      #pragma unroll
      for (int i = 0; i < 4; ++i) {
        int rl = set * 16 + quad * 4 + i;
        sm[wid][rl] = m[set][i]; ssh[wid][rl] = s[set][i]; sbi[wid][rl] = bi[set][i];
      }
  }

  // label-logit post-pass: 8 lanes per row (64 rows, 512 threads); bf16 dot
  // with the same rounding as the MFMA path. Lane l handles K-chunk kk=l.
  {
    const int rl = tid >> 3, l = tid & 7;
    const int row = r0 + rl;
    const int lab = label[row >> 3];
    const int kk  = l;
    float dot = 0.f;
    const size_t qc = ((size_t)(row >> 4) * 8 + kk) * 64 + (row & 15);
    const size_t ac = ((size_t)(lab >> 4) * 8 + kk) * 64 + (lab & 15);
    #pragma unroll
    for (int qd = 0; qd < 4; ++qd) {
      bf16x8 qv = qb[qc + qd * 16];
      bf16x8 av = bb[ac + qd * 16];
      #pragma unroll
      for (int j = 0; j < 8; ++j) dot = fmaf(bf2f(qv[j]), bf2f(av[j]), dot);
    }
    dot += __shfl_xor(dot, 1);
    dot += __shfl_xor(dot, 2);
    dot += __shfl_xor(dot, 4);
    if (l == 0) slab[rl] = fmaf(dot, 2.f * L2E, cb[lab]);  // shifted label logit
  }
  __syncthreads();

  if (tid < 64) {                                  // one full wave
    float mm = sm[0][tid], sv = ssh[0][tid];
    int   b  = sbi[0][tid];
    #pragma unroll
    for (int w = 1; w < 8; ++w) {                  // stripes in ascending col order
      float om = sm[w][tid], os = ssh[w][tid];
      int   oi = sbi[w][tid];
      float nm = fmaxf(mm, om);
      sv = sv * exp2f(mm - nm) + os * exp2f(om - nm);
      bool better = (om > mm) || (om == mm && oi < b);
      b = better ? oi : b;
      mm = nm;
    }
    const int row = r0 + tid;
    const int lb  = label[row >> 3];
    float loss = LN2 * (mm + log2f(sv) - slab[tid]);
    float corr = (b == lb) ? 1.f : 0.f;
    #pragma unroll
    for (int mask = 32; mask; mask >>= 1) {        // full-wave xor reduce
      loss += __shfl_xor(loss, mask);
      corr += __shfl_xor(corr, mask);
    }
    if (tid == 0) {
      atomicAdd(&accum[0], loss);
      atomicAdd(&accum[1], corr);
      __threadfence();
      if (atomicAdd(fincount, 1) == (int)gridDim.x - 1) {
        out[0] = atomicAdd(&accum[0], 0.f) / (float)NROW;   // coherent reads
        out[1] = atomicAdd(&accum[1], 0.f) * 100.f / (float)NROW;
      }
    }
  }
}

// ---------------------------------------------------------------------------
extern "C" void kernel_launch(void* const* d_in, const int* in_sizes, int n_in,
                              void* d_out, int out_size, void* d_ws, size_t ws_size,
                              hipStream_t stream) {
  const float* x     = (const float*)d_in[0];
  const int*   label = (const int*)d_in[1];
  float* out = (float*)d_out;

  // ws layout (float-sized slots): [0:2) accum | [2] fincount |
  // [16,16+NCOL) cb | Asw (NCOL*DD ushort) | Qsw (NROW*DD ushort)
  float*  W        = (float*)d_ws;
  float*  accum    = W;
  int*    fincount = (int*)(W + 2);
  float*  cb       = W + 16;
  ushort* Asw      = (ushort*)(cb + NCOL);
  ushort* Qsw      = Asw + (size_t)NCOL * DD;

  hipLaunchKernelGGL(proto_prep, dim3(NEP / 4), dim3(256), 0, stream,
                     x, cb, Asw, Qsw, accum, fincount);
  hipLaunchKernelGGL(proto_main, dim3(NROW / 64), dim3(512), 0, stream,
                     Qsw, Asw, cb, label, accum, fincount, out);
}